// Round 6
// baseline (606.874 us; speedup 1.0000x reference)
//
#include <hip/hip_runtime.h>

#define N_NODES 50000
#define N_EDGES 800000
#define E_TOT   850000      // + self loops
#define IN0     128
#define HID     96
#define NUM_GRAPHS 64
#define NB      ((N_NODES + 1023) / 1024)   // 49 scan blocks

__device__ __forceinline__ float leaky(float x, float s) { return x > 0.f ? x : s * x; }

// ---------------- CSR build ----------------
__global__ void count_deg(const int* __restrict__ dst, int* __restrict__ deg) {
    int e = blockIdx.x * blockDim.x + threadIdx.x;
    if (e >= E_TOT) return;
    int d = (e < N_EDGES) ? dst[e] : (e - N_EDGES);   // appended self loops
    atomicAdd(&deg[d], 1);
}

// 3-kernel multi-block exclusive scan of deg -> offs
__global__ __launch_bounds__(256) void block_sums(const int* __restrict__ deg, int* __restrict__ bsum) {
    int b = blockIdx.x, t = threadIdx.x;
    int base = b * 1024 + t * 4;
    int s = 0;
    if (base + 3 < N_NODES) {
        int4 v = *(const int4*)(deg + base);
        s = v.x + v.y + v.z + v.w;
    } else {
        for (int k = 0; k < 4; ++k) if (base + k < N_NODES) s += deg[base + k];
    }
#pragma unroll
    for (int w = 32; w >= 1; w >>= 1) s += __shfl_xor(s, w);
    __shared__ int ws[4];
    if ((t & 63) == 0) ws[t >> 6] = s;
    __syncthreads();
    if (t == 0) bsum[b] = ws[0] + ws[1] + ws[2] + ws[3];
}

__global__ void scan_partials(const int* __restrict__ bsum, int* __restrict__ excl, int* __restrict__ offs) {
    int t = threadIdx.x;   // 64 threads
    int v = (t < NB) ? bsum[t] : 0;
    int incl = v;
#pragma unroll
    for (int d = 1; d < 64; d <<= 1) {
        int u = __shfl_up(incl, d);
        if (t >= d) incl += u;
    }
    if (t < NB) excl[t] = incl - v;
    if (t == 0) offs[N_NODES] = E_TOT;
}

__global__ __launch_bounds__(256) void write_offs(const int* __restrict__ deg,
                                                  const int* __restrict__ excl,
                                                  int* __restrict__ offs) {
    __shared__ int sh[256];
    int b = blockIdx.x, t = threadIdx.x;
    int base = b * 1024 + t * 4;
    int d0 = 0, d1 = 0, d2 = 0, d3 = 0;
    if (base + 3 < N_NODES) {
        int4 v = *(const int4*)(deg + base);
        d0 = v.x; d1 = v.y; d2 = v.z; d3 = v.w;
    } else {
        if (base     < N_NODES) d0 = deg[base];
        if (base + 1 < N_NODES) d1 = deg[base + 1];
        if (base + 2 < N_NODES) d2 = deg[base + 2];
    }
    int tsum = d0 + d1 + d2 + d3;
    sh[t] = tsum;
    __syncthreads();
    for (int off = 1; off < 256; off <<= 1) {
        int u = (t >= off) ? sh[t - off] : 0;
        __syncthreads();
        sh[t] += u;
        __syncthreads();
    }
    int ebase = excl[b] + sh[t] - tsum;
    if (base + 3 < N_NODES) {
        int4 o; o.x = ebase; o.y = ebase + d0; o.z = ebase + d0 + d1; o.w = ebase + d0 + d1 + d2;
        *(int4*)(offs + base) = o;
    } else {
        if (base     < N_NODES) offs[base]     = ebase;
        if (base + 1 < N_NODES) offs[base + 1] = ebase + d0;
        if (base + 2 < N_NODES) offs[base + 2] = ebase + d0 + d1;
    }
}

__global__ void scatter_edges(const int* __restrict__ src, const int* __restrict__ dst,
                              const int* __restrict__ offs, int* __restrict__ cursor,
                              int* __restrict__ csr) {
    int e = blockIdx.x * blockDim.x + threadIdx.x;
    if (e >= E_TOT) return;
    int s, d;
    if (e < N_EDGES) { s = src[e]; d = dst[e]; }
    else             { s = e - N_EDGES; d = s; }
    int pos = offs[d] + atomicAdd(&cursor[d], 1);
    csr[pos] = s;
}

// ---------------- row-wise GEMM + attention logits (no LDS staging) ----------------
// block = 64 rows x 4 col-quarters (one wave per quarter). Thread owns 1 row x 24 cols.
// W/a_src/a_dst read with wave-uniform addresses -> compiler emits s_load (SGPR
// broadcast), so the only vector-memory traffic is each thread's own X row.
template <int IN>
__global__ __launch_bounds__(256) void gemm_rowwise(
    const float* __restrict__ X, const float* __restrict__ W,
    const float* __restrict__ asrc, const float* __restrict__ adst,
    float* __restrict__ H, float* __restrict__ As, float* __restrict__ Ad) {
    __shared__ float asP[256], adP[256];
    int t = threadIdx.x;
    int q = t >> 6;          // wave id = col quarter (uniform per wave)
    int r = t & 63;
    int row = blockIdx.x * 64 + r;
    int cbase = q * 24;
    bool valid = row < N_NODES;
    float ps = 0.f, pd = 0.f;
    if (valid) {
        const float* xr = X + (size_t)row * IN;
        const float* wq = W + cbase;
        float acc[24];
#pragma unroll
        for (int c = 0; c < 24; ++c) acc[c] = 0.f;
        for (int k = 0; k < IN; k += 4) {
            float4 xv = *(const float4*)(xr + k);
            const float* wp = wq + (size_t)k * HID;
#pragma unroll
            for (int c = 0; c < 24; ++c) {
                acc[c] += xv.x * wp[c];
                acc[c] += xv.y * wp[c + HID];
                acc[c] += xv.z * wp[c + 2 * HID];
                acc[c] += xv.w * wp[c + 3 * HID];
            }
        }
        // store H (6 float4, 16B aligned: row*96*4 and cbase*4 are 16B multiples)
        float* hr = H + (size_t)row * HID + cbase;
#pragma unroll
        for (int c = 0; c < 24; c += 4) {
            float4 o; o.x = acc[c]; o.y = acc[c + 1]; o.z = acc[c + 2]; o.w = acc[c + 3];
            *(float4*)(hr + c) = o;
        }
        // partial attention dots over this quarter (a vectors s_load uniform)
#pragma unroll
        for (int c = 0; c < 24; ++c) {
            ps += acc[c] * asrc[cbase + c];
            pd += acc[c] * adst[cbase + c];
        }
    }
    asP[t] = ps; adP[t] = pd;
    __syncthreads();
    if (t < 64) {
        int row0 = blockIdx.x * 64 + t;
        if (row0 < N_NODES) {
            As[row0] = asP[t] + asP[64 + t] + asP[128 + t] + asP[192 + t];
            Ad[row0] = adP[t] + adP[64 + t] + adP[128 + t] + adP[192 + t];
        }
    }
}

// ---------------- CSR softmax-aggregate (no max pass; shift by self-loop logit) --------
__global__ __launch_bounds__(256) void aggregate(
    const float* __restrict__ H, const float* __restrict__ As, const float* __restrict__ Ad,
    const int* __restrict__ offs, const int* __restrict__ csr,
    const float* __restrict__ bias, float* __restrict__ Hout, int apply_leaky) {
    int team = (blockIdx.x * blockDim.x + threadIdx.x) >> 5;   // == node
    int lane = threadIdx.x & 31;
    int half = threadIdx.x & 32;   // wave64 half base for shfl
    int start = offs[team], end = offs[team + 1];
    float ad = Ad[team];
    // softmax shift: self-loop logit (free, no gather; denom >= 1)
    float m = leaky(As[team] + ad, 0.2f);
    float acc0 = 0.f, acc1 = 0.f, acc2 = 0.f, denom = 0.f;
    int c = lane * 3;
    for (int base = start; base < end; base += 32) {
        int i = base + lane;
        bool valid = i < end;
        int s = valid ? csr[i] : 0;
        float ex = 0.f;
        if (valid) ex = __expf(leaky(As[s] + ad, 0.2f) - m);
        denom += ex;
        int cnt = min(32, end - base);
        int j = 0;
        for (; j + 8 <= cnt; j += 8) {
            float e[8]; int ss[8];
#pragma unroll
            for (int q = 0; q < 8; ++q) {
                e[q]  = __shfl(ex, half + j + q);
                ss[q] = __shfl(s,  half + j + q);
            }
            float v0[8], v1[8], v2[8];
#pragma unroll
            for (int q = 0; q < 8; ++q) {
                const float* p = H + (size_t)ss[q] * HID + c;
                v0[q] = p[0]; v1[q] = p[1]; v2[q] = p[2];
            }
#pragma unroll
            for (int q = 0; q < 8; ++q) {
                acc0 += e[q] * v0[q]; acc1 += e[q] * v1[q]; acc2 += e[q] * v2[q];
            }
        }
        for (; j + 4 <= cnt; j += 4) {
            float e[4]; int ss[4];
#pragma unroll
            for (int q = 0; q < 4; ++q) {
                e[q]  = __shfl(ex, half + j + q);
                ss[q] = __shfl(s,  half + j + q);
            }
            float v0[4], v1[4], v2[4];
#pragma unroll
            for (int q = 0; q < 4; ++q) {
                const float* p = H + (size_t)ss[q] * HID + c;
                v0[q] = p[0]; v1[q] = p[1]; v2[q] = p[2];
            }
#pragma unroll
            for (int q = 0; q < 4; ++q) {
                acc0 += e[q] * v0[q]; acc1 += e[q] * v1[q]; acc2 += e[q] * v2[q];
            }
        }
        for (; j < cnt; ++j) {
            float bex = __shfl(ex, half + j);
            int   bs  = __shfl(s,  half + j);
            const float* hp = H + (size_t)bs * HID + c;
            acc0 += bex * hp[0]; acc1 += bex * hp[1]; acc2 += bex * hp[2];
        }
    }
#pragma unroll
    for (int w = 16; w >= 1; w >>= 1) denom += __shfl_xor(denom, w);
    float inv = 1.f / (denom + 1e-16f);
    float o0 = acc0 * inv + bias[c];
    float o1 = acc1 * inv + bias[c + 1];
    float o2 = acc2 * inv + bias[c + 2];
    if (apply_leaky) { o0 = leaky(o0, 0.01f); o1 = leaky(o1, 0.01f); o2 = leaky(o2, 0.01f); }
    Hout[team * HID + c]     = o0;
    Hout[team * HID + c + 1] = o1;
    Hout[team * HID + c + 2] = o2;
}

// ---------------- global mean pool (fused count+sum, batch sorted) ----------------
__global__ __launch_bounds__(256) void pool_sum(
    const float* __restrict__ H, const int* __restrict__ batch,
    float* __restrict__ sums, float* __restrict__ counts) {
    int team = (blockIdx.x * blockDim.x + threadIdx.x) >> 5;
    int lane = threadIdx.x & 31;
    int c = lane * 3;
    int n0 = team * 32;
    if (n0 >= N_NODES) return;
    int n1 = min(n0 + 32, N_NODES);
    float a0 = 0.f, a1 = 0.f, a2 = 0.f;
    int cur = batch[n0], runlen = 0;
    for (int n = n0; n < n1; ++n) {
        int g = batch[n];
        if (g != cur) {
            atomicAdd(&sums[cur * HID + c],     a0);
            atomicAdd(&sums[cur * HID + c + 1], a1);
            atomicAdd(&sums[cur * HID + c + 2], a2);
            if (lane == 0) atomicAdd(&counts[cur], (float)runlen);
            a0 = a1 = a2 = 0.f; cur = g; runlen = 0;
        }
        const float* hp = H + (size_t)n * HID + c;
        a0 += hp[0]; a1 += hp[1]; a2 += hp[2];
        ++runlen;
    }
    atomicAdd(&sums[cur * HID + c],     a0);
    atomicAdd(&sums[cur * HID + c + 1], a1);
    atomicAdd(&sums[cur * HID + c + 2], a2);
    if (lane == 0) atomicAdd(&counts[cur], (float)runlen);
}

__global__ void finalize(const float* __restrict__ sums, const float* __restrict__ counts,
                         float* __restrict__ out) {
    int i = blockIdx.x * blockDim.x + threadIdx.x;
    if (i < NUM_GRAPHS * HID) out[i] = sums[i] / fmaxf(counts[i / HID], 1.f);
}

// ---------------- launch ----------------
extern "C" void kernel_launch(void* const* d_in, const int* in_sizes, int n_in,
                              void* d_out, int out_size, void* d_ws, size_t ws_size,
                              hipStream_t stream) {
    const float* x     = (const float*)d_in[0];
    const int*   ei    = (const int*)d_in[1];
    const int*   srcI  = ei;
    const int*   dstI  = ei + N_EDGES;
    const int*   batch = (const int*)d_in[2];
    const float* W1 = (const float*)d_in[3],  *as1 = (const float*)d_in[4],
               * ad1 = (const float*)d_in[5], *b1  = (const float*)d_in[6];
    const float* W2 = (const float*)d_in[7],  *as2 = (const float*)d_in[8],
               * ad2 = (const float*)d_in[9], *b2  = (const float*)d_in[10];
    const float* W3 = (const float*)d_in[11], *as3 = (const float*)d_in[12],
               * ad3 = (const float*)d_in[13], *b3 = (const float*)d_in[14];
    float* out = (float*)d_out;

    // workspace layout (all 16B-aligned by construction)
    char* p = (char*)d_ws;
    float* h0 = (float*)p;  p += (size_t)N_NODES * HID * 4;
    float* h1 = (float*)p;  p += (size_t)N_NODES * HID * 4;
    float* As = (float*)p;  p += (size_t)N_NODES * 4;
    float* Ad = (float*)p;  p += (size_t)N_NODES * 4;
    int* offs = (int*)p;    p += (size_t)(N_NODES + 4) * 4;
    int* csr  = (int*)p;    p += (size_t)E_TOT * 4;
    int* bsum = (int*)p;    p += 64 * 4;
    int* excl = (int*)p;    p += 64 * 4;
    // contiguous zero-region: sums | counts | deg | cursor
    char* zbase = p;
    float* sums   = (float*)p; p += (size_t)NUM_GRAPHS * HID * 4;
    float* counts = (float*)p; p += (size_t)NUM_GRAPHS * 4;
    int* deg    = (int*)p;  p += (size_t)N_NODES * 4;
    int* cursor = (int*)p;  p += (size_t)N_NODES * 4;
    size_t zbytes = (size_t)(p - zbase);

    hipMemsetAsync(zbase, 0, zbytes, stream);

    int eb = (E_TOT + 255) / 256;
    count_deg<<<eb, 256, 0, stream>>>(dstI, deg);
    block_sums<<<NB, 256, 0, stream>>>(deg, bsum);
    scan_partials<<<1, 64, 0, stream>>>(bsum, excl, offs);
    write_offs<<<NB, 256, 0, stream>>>(deg, excl, offs);
    scatter_edges<<<eb, 256, 0, stream>>>(srcI, dstI, offs, cursor, csr);

    int gemmGrid = (N_NODES + 63) / 64;    // 782 blocks, 64 rows x 4 quarters each
    int aggGrid  = (N_NODES * 32) / 256;   // exact: 6250

    // layer 1
    gemm_rowwise<IN0><<<gemmGrid, 256, 0, stream>>>(x, W1, as1, ad1, h0, As, Ad);
    aggregate<<<aggGrid, 256, 0, stream>>>(h0, As, Ad, offs, csr, b1, h1, 1);
    // layer 2
    gemm_rowwise<HID><<<gemmGrid, 256, 0, stream>>>(h1, W2, as2, ad2, h0, As, Ad);
    aggregate<<<aggGrid, 256, 0, stream>>>(h0, As, Ad, offs, csr, b2, h1, 1);
    // layer 3
    gemm_rowwise<HID><<<gemmGrid, 256, 0, stream>>>(h1, W3, as3, ad3, h0, As, Ad);
    aggregate<<<aggGrid, 256, 0, stream>>>(h0, As, Ad, offs, csr, b3, h1, 0);

    // mean pool
    int teams = (N_NODES + 31) / 32;
    pool_sum<<<(teams * 32 + 255) / 256, 256, 0, stream>>>(h1, batch, sums, counts);
    finalize<<<(NUM_GRAPHS * HID + 255) / 256, 256, 0, stream>>>(sums, counts, out);
}

// Round 7
// 512.294 us; speedup vs baseline: 1.1846x; 1.1846x over previous
//
#include <hip/hip_runtime.h>

#define N_NODES 50000
#define N_EDGES 800000
#define E_TOT   850000      // + self loops
#define IN0     128
#define HID     96
#define NUM_GRAPHS 64
#define NB      ((N_NODES + 1023) / 1024)   // 49 scan blocks

__device__ __forceinline__ float leaky(float x, float s) { return x > 0.f ? x : s * x; }

// ---------------- CSR build ----------------
__global__ void count_deg(const int* __restrict__ dst, int* __restrict__ deg) {
    int e = blockIdx.x * blockDim.x + threadIdx.x;
    if (e >= E_TOT) return;
    int d = (e < N_EDGES) ? dst[e] : (e - N_EDGES);   // appended self loops
    atomicAdd(&deg[d], 1);
}

// 3-kernel multi-block exclusive scan of deg -> offs
__global__ __launch_bounds__(256) void block_sums(const int* __restrict__ deg, int* __restrict__ bsum) {
    int b = blockIdx.x, t = threadIdx.x;
    int base = b * 1024 + t * 4;
    int s = 0;
    if (base + 3 < N_NODES) {
        int4 v = *(const int4*)(deg + base);
        s = v.x + v.y + v.z + v.w;
    } else {
        for (int k = 0; k < 4; ++k) if (base + k < N_NODES) s += deg[base + k];
    }
#pragma unroll
    for (int w = 32; w >= 1; w >>= 1) s += __shfl_xor(s, w);
    __shared__ int ws[4];
    if ((t & 63) == 0) ws[t >> 6] = s;
    __syncthreads();
    if (t == 0) bsum[b] = ws[0] + ws[1] + ws[2] + ws[3];
}

__global__ void scan_partials(const int* __restrict__ bsum, int* __restrict__ excl, int* __restrict__ offs) {
    int t = threadIdx.x;   // 64 threads
    int v = (t < NB) ? bsum[t] : 0;
    int incl = v;
#pragma unroll
    for (int d = 1; d < 64; d <<= 1) {
        int u = __shfl_up(incl, d);
        if (t >= d) incl += u;
    }
    if (t < NB) excl[t] = incl - v;
    if (t == 0) offs[N_NODES] = E_TOT;
}

__global__ __launch_bounds__(256) void write_offs(const int* __restrict__ deg,
                                                  const int* __restrict__ excl,
                                                  int* __restrict__ offs) {
    __shared__ int sh[256];
    int b = blockIdx.x, t = threadIdx.x;
    int base = b * 1024 + t * 4;
    int d0 = 0, d1 = 0, d2 = 0, d3 = 0;
    if (base + 3 < N_NODES) {
        int4 v = *(const int4*)(deg + base);
        d0 = v.x; d1 = v.y; d2 = v.z; d3 = v.w;
    } else {
        if (base     < N_NODES) d0 = deg[base];
        if (base + 1 < N_NODES) d1 = deg[base + 1];
        if (base + 2 < N_NODES) d2 = deg[base + 2];
    }
    int tsum = d0 + d1 + d2 + d3;
    sh[t] = tsum;
    __syncthreads();
    for (int off = 1; off < 256; off <<= 1) {
        int u = (t >= off) ? sh[t - off] : 0;
        __syncthreads();
        sh[t] += u;
        __syncthreads();
    }
    int ebase = excl[b] + sh[t] - tsum;
    if (base + 3 < N_NODES) {
        int4 o; o.x = ebase; o.y = ebase + d0; o.z = ebase + d0 + d1; o.w = ebase + d0 + d1 + d2;
        *(int4*)(offs + base) = o;
    } else {
        if (base     < N_NODES) offs[base]     = ebase;
        if (base + 1 < N_NODES) offs[base + 1] = ebase + d0;
        if (base + 2 < N_NODES) offs[base + 2] = ebase + d0 + d1;
    }
}

__global__ void scatter_edges(const int* __restrict__ src, const int* __restrict__ dst,
                              const int* __restrict__ offs, int* __restrict__ cursor,
                              int* __restrict__ csr) {
    int e = blockIdx.x * blockDim.x + threadIdx.x;
    if (e >= E_TOT) return;
    int s, d;
    if (e < N_EDGES) { s = src[e]; d = dst[e]; }
    else             { s = e - N_EDGES; d = s; }
    int pos = offs[d] + atomicAdd(&cursor[d], 1);
    csr[pos] = s;
}

// ---------------- K-tiled GEMM + attention logits ----------------
// block = 64 rows x 96 cols, K tiled by 32. Thread (cx=tid&31, ry=tid>>5) owns
// 8 rows x 3 cols. W staged TRANSPOSED in LDS (Wt[c][k], stride 36 words) so
// all inner-loop LDS reads are ds_read_b128: 11 reads per 96 FMAs.
template <int IN>
__global__ __launch_bounds__(256) void gemm_tiled(
    const float* __restrict__ X, const float* __restrict__ W,
    const float* __restrict__ asrc, const float* __restrict__ adst,
    float* __restrict__ H, float* __restrict__ As, float* __restrict__ Ad) {
    __shared__ float Xs[64 * 36];   // 9216 B
    __shared__ float Wt[96 * 36];   // 13824 B
    int tid = threadIdx.x;
    int cx = tid & 31, ry = tid >> 5;
    int cbase = cx * 3;
    int rowBase = blockIdx.x * 64;
    float acc[8][3];
#pragma unroll
    for (int r = 0; r < 8; ++r)
#pragma unroll
        for (int j = 0; j < 3; ++j) acc[r][j] = 0.f;

    for (int t = 0; t < IN / 32; ++t) {
        int k0 = t * 32;
        __syncthreads();   // previous tile's reads done before overwrite
        // stage X tile: 64 rows x 32 k (512 float4, 2 per thread)
#pragma unroll
        for (int j = 0; j < 2; ++j) {
            int f = tid * 2 + j;
            int row = f >> 3;
            int kk = (f & 7) * 4;
            int grow = rowBase + row;
            float4 v = make_float4(0.f, 0.f, 0.f, 0.f);
            if (grow < N_NODES) v = *(const float4*)(X + (size_t)grow * IN + k0 + kk);
            *(float4*)(&Xs[row * 36 + kk]) = v;
        }
        // stage W tile transposed: 32 k x 96 c -> Wt[c][k] (12 floats per thread)
#pragma unroll
        for (int j = 0; j < 12; ++j) {
            int f = tid + j * 256;
            int kk = f / 96;
            int c = f - kk * 96;
            Wt[c * 36 + kk] = W[(size_t)(k0 + kk) * HID + c];
        }
        __syncthreads();
        // compute: all b128 LDS reads
#pragma unroll
        for (int k = 0; k < 32; k += 4) {
            float4 w0 = *(const float4*)(&Wt[(cbase + 0) * 36 + k]);
            float4 w1 = *(const float4*)(&Wt[(cbase + 1) * 36 + k]);
            float4 w2 = *(const float4*)(&Wt[(cbase + 2) * 36 + k]);
#pragma unroll
            for (int r = 0; r < 8; ++r) {
                float4 xv = *(const float4*)(&Xs[(ry * 8 + r) * 36 + k]);
                acc[r][0] += xv.x * w0.x + xv.y * w0.y + xv.z * w0.z + xv.w * w0.w;
                acc[r][1] += xv.x * w1.x + xv.y * w1.y + xv.z * w1.z + xv.w * w1.w;
                acc[r][2] += xv.x * w2.x + xv.y * w2.y + xv.z * w2.z + xv.w * w2.w;
            }
        }
    }
    // epilogue: store H, alpha dots, 32-lane shfl reduce
    float a0 = asrc[cbase], a1 = asrc[cbase + 1], a2 = asrc[cbase + 2];
    float d0 = adst[cbase], d1 = adst[cbase + 1], d2 = adst[cbase + 2];
#pragma unroll
    for (int r = 0; r < 8; ++r) {
        int row = rowBase + ry * 8 + r;
        bool valid = row < N_NODES;   // uniform across the 32 cx lanes
        float ps = acc[r][0] * a0 + acc[r][1] * a1 + acc[r][2] * a2;
        float pd = acc[r][0] * d0 + acc[r][1] * d1 + acc[r][2] * d2;
#pragma unroll
        for (int w = 16; w >= 1; w >>= 1) {
            ps += __shfl_xor(ps, w);
            pd += __shfl_xor(pd, w);
        }
        if (valid) {
            float* hr = H + (size_t)row * HID + cbase;
            hr[0] = acc[r][0]; hr[1] = acc[r][1]; hr[2] = acc[r][2];
            if (cx == 0) { As[row] = ps; Ad[row] = pd; }
        }
    }
}

// ---------------- CSR softmax-aggregate (no max pass; shift by self-loop logit) --------
__global__ __launch_bounds__(256) void aggregate(
    const float* __restrict__ H, const float* __restrict__ As, const float* __restrict__ Ad,
    const int* __restrict__ offs, const int* __restrict__ csr,
    const float* __restrict__ bias, float* __restrict__ Hout, int apply_leaky) {
    int team = (blockIdx.x * blockDim.x + threadIdx.x) >> 5;   // == node
    int lane = threadIdx.x & 31;
    int half = threadIdx.x & 32;   // wave64 half base for shfl
    int start = offs[team], end = offs[team + 1];
    float ad = Ad[team];
    // softmax shift: self-loop logit (free, no gather; denom >= 1)
    float m = leaky(As[team] + ad, 0.2f);
    float acc0 = 0.f, acc1 = 0.f, acc2 = 0.f, denom = 0.f;
    int c = lane * 3;
    for (int base = start; base < end; base += 32) {
        int i = base + lane;
        bool valid = i < end;
        int s = valid ? csr[i] : 0;
        float ex = 0.f;
        if (valid) ex = __expf(leaky(As[s] + ad, 0.2f) - m);
        denom += ex;
        int cnt = min(32, end - base);
        int j = 0;
        for (; j + 8 <= cnt; j += 8) {
            float e[8]; int ss[8];
#pragma unroll
            for (int q = 0; q < 8; ++q) {
                e[q]  = __shfl(ex, half + j + q);
                ss[q] = __shfl(s,  half + j + q);
            }
            float v0[8], v1[8], v2[8];
#pragma unroll
            for (int q = 0; q < 8; ++q) {
                const float* p = H + (size_t)ss[q] * HID + c;
                v0[q] = p[0]; v1[q] = p[1]; v2[q] = p[2];
            }
#pragma unroll
            for (int q = 0; q < 8; ++q) {
                acc0 += e[q] * v0[q]; acc1 += e[q] * v1[q]; acc2 += e[q] * v2[q];
            }
        }
        for (; j + 4 <= cnt; j += 4) {
            float e[4]; int ss[4];
#pragma unroll
            for (int q = 0; q < 4; ++q) {
                e[q]  = __shfl(ex, half + j + q);
                ss[q] = __shfl(s,  half + j + q);
            }
            float v0[4], v1[4], v2[4];
#pragma unroll
            for (int q = 0; q < 4; ++q) {
                const float* p = H + (size_t)ss[q] * HID + c;
                v0[q] = p[0]; v1[q] = p[1]; v2[q] = p[2];
            }
#pragma unroll
            for (int q = 0; q < 4; ++q) {
                acc0 += e[q] * v0[q]; acc1 += e[q] * v1[q]; acc2 += e[q] * v2[q];
            }
        }
        for (; j < cnt; ++j) {
            float bex = __shfl(ex, half + j);
            int   bs  = __shfl(s,  half + j);
            const float* hp = H + (size_t)bs * HID + c;
            acc0 += bex * hp[0]; acc1 += bex * hp[1]; acc2 += bex * hp[2];
        }
    }
#pragma unroll
    for (int w = 16; w >= 1; w >>= 1) denom += __shfl_xor(denom, w);
    float inv = 1.f / (denom + 1e-16f);
    float o0 = acc0 * inv + bias[c];
    float o1 = acc1 * inv + bias[c + 1];
    float o2 = acc2 * inv + bias[c + 2];
    if (apply_leaky) { o0 = leaky(o0, 0.01f); o1 = leaky(o1, 0.01f); o2 = leaky(o2, 0.01f); }
    Hout[team * HID + c]     = o0;
    Hout[team * HID + c + 1] = o1;
    Hout[team * HID + c + 2] = o2;
}

// ---------------- global mean pool (fused count+sum, batch sorted) ----------------
__global__ __launch_bounds__(256) void pool_sum(
    const float* __restrict__ H, const int* __restrict__ batch,
    float* __restrict__ sums, float* __restrict__ counts) {
    int team = (blockIdx.x * blockDim.x + threadIdx.x) >> 5;
    int lane = threadIdx.x & 31;
    int c = lane * 3;
    int n0 = team * 32;
    if (n0 >= N_NODES) return;
    int n1 = min(n0 + 32, N_NODES);
    float a0 = 0.f, a1 = 0.f, a2 = 0.f;
    int cur = batch[n0], runlen = 0;
    for (int n = n0; n < n1; ++n) {
        int g = batch[n];
        if (g != cur) {
            atomicAdd(&sums[cur * HID + c],     a0);
            atomicAdd(&sums[cur * HID + c + 1], a1);
            atomicAdd(&sums[cur * HID + c + 2], a2);
            if (lane == 0) atomicAdd(&counts[cur], (float)runlen);
            a0 = a1 = a2 = 0.f; cur = g; runlen = 0;
        }
        const float* hp = H + (size_t)n * HID + c;
        a0 += hp[0]; a1 += hp[1]; a2 += hp[2];
        ++runlen;
    }
    atomicAdd(&sums[cur * HID + c],     a0);
    atomicAdd(&sums[cur * HID + c + 1], a1);
    atomicAdd(&sums[cur * HID + c + 2], a2);
    if (lane == 0) atomicAdd(&counts[cur], (float)runlen);
}

__global__ void finalize(const float* __restrict__ sums, const float* __restrict__ counts,
                         float* __restrict__ out) {
    int i = blockIdx.x * blockDim.x + threadIdx.x;
    if (i < NUM_GRAPHS * HID) out[i] = sums[i] / fmaxf(counts[i / HID], 1.f);
}

// ---------------- launch ----------------
extern "C" void kernel_launch(void* const* d_in, const int* in_sizes, int n_in,
                              void* d_out, int out_size, void* d_ws, size_t ws_size,
                              hipStream_t stream) {
    const float* x     = (const float*)d_in[0];
    const int*   ei    = (const int*)d_in[1];
    const int*   srcI  = ei;
    const int*   dstI  = ei + N_EDGES;
    const int*   batch = (const int*)d_in[2];
    const float* W1 = (const float*)d_in[3],  *as1 = (const float*)d_in[4],
               * ad1 = (const float*)d_in[5], *b1  = (const float*)d_in[6];
    const float* W2 = (const float*)d_in[7],  *as2 = (const float*)d_in[8],
               * ad2 = (const float*)d_in[9], *b2  = (const float*)d_in[10];
    const float* W3 = (const float*)d_in[11], *as3 = (const float*)d_in[12],
               * ad3 = (const float*)d_in[13], *b3 = (const float*)d_in[14];
    float* out = (float*)d_out;

    // workspace layout (all 16B-aligned by construction)
    char* p = (char*)d_ws;
    float* h0 = (float*)p;  p += (size_t)N_NODES * HID * 4;
    float* h1 = (float*)p;  p += (size_t)N_NODES * HID * 4;
    float* As = (float*)p;  p += (size_t)N_NODES * 4;
    float* Ad = (float*)p;  p += (size_t)N_NODES * 4;
    int* offs = (int*)p;    p += (size_t)(N_NODES + 4) * 4;
    int* csr  = (int*)p;    p += (size_t)E_TOT * 4;
    int* bsum = (int*)p;    p += 64 * 4;
    int* excl = (int*)p;    p += 64 * 4;
    // contiguous zero-region: sums | counts | deg | cursor
    char* zbase = p;
    float* sums   = (float*)p; p += (size_t)NUM_GRAPHS * HID * 4;
    float* counts = (float*)p; p += (size_t)NUM_GRAPHS * 4;
    int* deg    = (int*)p;  p += (size_t)N_NODES * 4;
    int* cursor = (int*)p;  p += (size_t)N_NODES * 4;
    size_t zbytes = (size_t)(p - zbase);

    hipMemsetAsync(zbase, 0, zbytes, stream);

    int eb = (E_TOT + 255) / 256;
    count_deg<<<eb, 256, 0, stream>>>(dstI, deg);
    block_sums<<<NB, 256, 0, stream>>>(deg, bsum);
    scan_partials<<<1, 64, 0, stream>>>(bsum, excl, offs);
    write_offs<<<NB, 256, 0, stream>>>(deg, excl, offs);
    scatter_edges<<<eb, 256, 0, stream>>>(srcI, dstI, offs, cursor, csr);

    int gemmGrid = (N_NODES + 63) / 64;    // 782 blocks
    int aggGrid  = (N_NODES * 32) / 256;   // exact: 6250

    // layer 1
    gemm_tiled<IN0><<<gemmGrid, 256, 0, stream>>>(x, W1, as1, ad1, h0, As, Ad);
    aggregate<<<aggGrid, 256, 0, stream>>>(h0, As, Ad, offs, csr, b1, h1, 1);
    // layer 2
    gemm_tiled<HID><<<gemmGrid, 256, 0, stream>>>(h1, W2, as2, ad2, h0, As, Ad);
    aggregate<<<aggGrid, 256, 0, stream>>>(h0, As, Ad, offs, csr, b2, h1, 1);
    // layer 3
    gemm_tiled<HID><<<gemmGrid, 256, 0, stream>>>(h1, W3, as3, ad3, h0, As, Ad);
    aggregate<<<aggGrid, 256, 0, stream>>>(h0, As, Ad, offs, csr, b3, h1, 0);

    // mean pool
    int teams = (N_NODES + 31) / 32;
    pool_sum<<<(teams * 32 + 255) / 256, 256, 0, stream>>>(h1, batch, sums, counts);
    finalize<<<(NUM_GRAPHS * HID + 255) / 256, 256, 0, stream>>>(sums, counts, out);
}

// Round 8
// 494.180 us; speedup vs baseline: 1.2280x; 1.0367x over previous
//
#include <hip/hip_runtime.h>

#define N_NODES 50000
#define N_EDGES 800000
#define E_TOT   850000      // + self loops
#define IN0     128
#define HID     96
#define NUM_GRAPHS 64
#define NB      ((N_NODES + 1023) / 1024)   // 49 scan blocks

__device__ __forceinline__ float leaky(float x, float s) { return x > 0.f ? x : s * x; }

// ---------------- CSR build ----------------
__global__ void count_deg(const int* __restrict__ dst, int* __restrict__ deg) {
    int e = blockIdx.x * blockDim.x + threadIdx.x;
    if (e >= E_TOT) return;
    int d = (e < N_EDGES) ? dst[e] : (e - N_EDGES);   // appended self loops
    atomicAdd(&deg[d], 1);
}

// 3-kernel multi-block exclusive scan of deg -> offs
__global__ __launch_bounds__(256) void block_sums(const int* __restrict__ deg, int* __restrict__ bsum) {
    int b = blockIdx.x, t = threadIdx.x;
    int base = b * 1024 + t * 4;
    int s = 0;
    if (base + 3 < N_NODES) {
        int4 v = *(const int4*)(deg + base);
        s = v.x + v.y + v.z + v.w;
    } else {
        for (int k = 0; k < 4; ++k) if (base + k < N_NODES) s += deg[base + k];
    }
#pragma unroll
    for (int w = 32; w >= 1; w >>= 1) s += __shfl_xor(s, w);
    __shared__ int ws[4];
    if ((t & 63) == 0) ws[t >> 6] = s;
    __syncthreads();
    if (t == 0) bsum[b] = ws[0] + ws[1] + ws[2] + ws[3];
}

__global__ void scan_partials(const int* __restrict__ bsum, int* __restrict__ excl, int* __restrict__ offs) {
    int t = threadIdx.x;   // 64 threads
    int v = (t < NB) ? bsum[t] : 0;
    int incl = v;
#pragma unroll
    for (int d = 1; d < 64; d <<= 1) {
        int u = __shfl_up(incl, d);
        if (t >= d) incl += u;
    }
    if (t < NB) excl[t] = incl - v;
    if (t == 0) offs[N_NODES] = E_TOT;
}

__global__ __launch_bounds__(256) void write_offs(const int* __restrict__ deg,
                                                  const int* __restrict__ excl,
                                                  int* __restrict__ offs) {
    __shared__ int sh[256];
    int b = blockIdx.x, t = threadIdx.x;
    int base = b * 1024 + t * 4;
    int d0 = 0, d1 = 0, d2 = 0, d3 = 0;
    if (base + 3 < N_NODES) {
        int4 v = *(const int4*)(deg + base);
        d0 = v.x; d1 = v.y; d2 = v.z; d3 = v.w;
    } else {
        if (base     < N_NODES) d0 = deg[base];
        if (base + 1 < N_NODES) d1 = deg[base + 1];
        if (base + 2 < N_NODES) d2 = deg[base + 2];
    }
    int tsum = d0 + d1 + d2 + d3;
    sh[t] = tsum;
    __syncthreads();
    for (int off = 1; off < 256; off <<= 1) {
        int u = (t >= off) ? sh[t - off] : 0;
        __syncthreads();
        sh[t] += u;
        __syncthreads();
    }
    int ebase = excl[b] + sh[t] - tsum;
    if (base + 3 < N_NODES) {
        int4 o; o.x = ebase; o.y = ebase + d0; o.z = ebase + d0 + d1; o.w = ebase + d0 + d1 + d2;
        *(int4*)(offs + base) = o;
    } else {
        if (base     < N_NODES) offs[base]     = ebase;
        if (base + 1 < N_NODES) offs[base + 1] = ebase + d0;
        if (base + 2 < N_NODES) offs[base + 2] = ebase + d0 + d1;
    }
}

__global__ void scatter_edges(const int* __restrict__ src, const int* __restrict__ dst,
                              const int* __restrict__ offs, int* __restrict__ cursor,
                              int* __restrict__ csr) {
    int e = blockIdx.x * blockDim.x + threadIdx.x;
    if (e >= E_TOT) return;
    int s, d;
    if (e < N_EDGES) { s = src[e]; d = dst[e]; }
    else             { s = e - N_EDGES; d = s; }
    int pos = offs[d] + atomicAdd(&cursor[d], 1);
    csr[pos] = s;
}

// ---------------- K-tiled GEMM + attention logits ----------------
// block = 64 rows x 96 cols, K tiled by 32. Thread (cx=tid&31, ry=tid>>5) owns
// 8 rows x 3 cols. W staged TRANSPOSED in LDS (Wt[c][k], stride 36 words):
// inner loop is all ds_read_b128. launch_bounds(256,4) caps VGPR <= 128 so we
// keep >=4 waves/SIMD (R7's 216-VGPR/8% occupancy was latency-bound).
template <int IN>
__global__ __launch_bounds__(256, 4) void gemm_tiled(
    const float* __restrict__ X, const float* __restrict__ W,
    const float* __restrict__ asrc, const float* __restrict__ adst,
    float* __restrict__ H, float* __restrict__ As, float* __restrict__ Ad) {
    __shared__ float Xs[64 * 36];   // 9216 B
    __shared__ float Wt[96 * 36];   // 13824 B
    int tid = threadIdx.x;
    int cx = tid & 31, ry = tid >> 5;
    int cbase = cx * 3;
    int rowBase = blockIdx.x * 64;
    const float* w0p = &Wt[(cbase + 0) * 36];
    const float* w1p = &Wt[(cbase + 1) * 36];
    const float* w2p = &Wt[(cbase + 2) * 36];
    const float* xsp = &Xs[ry * 8 * 36];
    float acc[8][3];
#pragma unroll
    for (int r = 0; r < 8; ++r)
#pragma unroll
        for (int j = 0; j < 3; ++j) acc[r][j] = 0.f;

    for (int t = 0; t < IN / 32; ++t) {
        int k0 = t * 32;
        __syncthreads();   // previous tile's reads done before overwrite
        // stage X tile: 64 rows x 32 k (512 float4, 2 per thread)
#pragma unroll
        for (int j = 0; j < 2; ++j) {
            int f = tid * 2 + j;
            int row = f >> 3;
            int kk = (f & 7) * 4;
            int grow = rowBase + row;
            float4 v = make_float4(0.f, 0.f, 0.f, 0.f);
            if (grow < N_NODES) v = *(const float4*)(X + (size_t)grow * IN + k0 + kk);
            *(float4*)(&Xs[row * 36 + kk]) = v;
        }
        // stage W tile transposed: 32 k x 96 c -> Wt[c][k] (12 floats per thread)
#pragma unroll
        for (int j = 0; j < 12; ++j) {
            int f = tid + j * 256;
            int kk = f / 96;
            int c = f - kk * 96;
            Wt[c * 36 + kk] = W[(size_t)(k0 + kk) * HID + c];
        }
        __syncthreads();
        // compute: all b128 LDS reads; unroll 2 keeps register pressure bounded
#pragma unroll 2
        for (int k = 0; k < 32; k += 4) {
            float4 w0 = *(const float4*)(w0p + k);
            float4 w1 = *(const float4*)(w1p + k);
            float4 w2 = *(const float4*)(w2p + k);
#pragma unroll
            for (int r = 0; r < 8; ++r) {
                float4 xv = *(const float4*)(xsp + r * 36 + k);
                acc[r][0] += xv.x * w0.x + xv.y * w0.y + xv.z * w0.z + xv.w * w0.w;
                acc[r][1] += xv.x * w1.x + xv.y * w1.y + xv.z * w1.z + xv.w * w1.w;
                acc[r][2] += xv.x * w2.x + xv.y * w2.y + xv.z * w2.z + xv.w * w2.w;
            }
        }
    }
    // epilogue: store H, alpha dots, 32-lane shfl reduce
    float a0 = asrc[cbase], a1 = asrc[cbase + 1], a2 = asrc[cbase + 2];
    float d0 = adst[cbase], d1 = adst[cbase + 1], d2 = adst[cbase + 2];
#pragma unroll
    for (int r = 0; r < 8; ++r) {
        int row = rowBase + ry * 8 + r;
        bool valid = row < N_NODES;   // uniform across the 32 cx lanes
        float ps = acc[r][0] * a0 + acc[r][1] * a1 + acc[r][2] * a2;
        float pd = acc[r][0] * d0 + acc[r][1] * d1 + acc[r][2] * d2;
#pragma unroll
        for (int w = 16; w >= 1; w >>= 1) {
            ps += __shfl_xor(ps, w);
            pd += __shfl_xor(pd, w);
        }
        if (valid) {
            float* hr = H + (size_t)row * HID + cbase;
            hr[0] = acc[r][0]; hr[1] = acc[r][1]; hr[2] = acc[r][2];
            if (cx == 0) { As[row] = ps; Ad[row] = pd; }
        }
    }
}

// ---------------- CSR softmax-aggregate (no max pass; shift by self-loop logit) --------
__global__ __launch_bounds__(256) void aggregate(
    const float* __restrict__ H, const float* __restrict__ As, const float* __restrict__ Ad,
    const int* __restrict__ offs, const int* __restrict__ csr,
    const float* __restrict__ bias, float* __restrict__ Hout, int apply_leaky) {
    int team = (blockIdx.x * blockDim.x + threadIdx.x) >> 5;   // == node
    int lane = threadIdx.x & 31;
    int half = threadIdx.x & 32;   // wave64 half base for shfl
    int start = offs[team], end = offs[team + 1];
    float ad = Ad[team];
    // softmax shift: self-loop logit (free, no gather; denom >= 1)
    float m = leaky(As[team] + ad, 0.2f);
    float acc0 = 0.f, acc1 = 0.f, acc2 = 0.f, denom = 0.f;
    int c = lane * 3;
    for (int base = start; base < end; base += 32) {
        int i = base + lane;
        bool valid = i < end;
        int s = valid ? csr[i] : 0;
        float ex = 0.f;
        if (valid) ex = __expf(leaky(As[s] + ad, 0.2f) - m);
        denom += ex;
        int cnt = min(32, end - base);
        int j = 0;
        for (; j + 8 <= cnt; j += 8) {
            float e[8]; int ss[8];
#pragma unroll
            for (int q = 0; q < 8; ++q) {
                e[q]  = __shfl(ex, half + j + q);
                ss[q] = __shfl(s,  half + j + q);
            }
            float v0[8], v1[8], v2[8];
#pragma unroll
            for (int q = 0; q < 8; ++q) {
                const float* p = H + (size_t)ss[q] * HID + c;
                v0[q] = p[0]; v1[q] = p[1]; v2[q] = p[2];
            }
#pragma unroll
            for (int q = 0; q < 8; ++q) {
                acc0 += e[q] * v0[q]; acc1 += e[q] * v1[q]; acc2 += e[q] * v2[q];
            }
        }
        for (; j + 4 <= cnt; j += 4) {
            float e[4]; int ss[4];
#pragma unroll
            for (int q = 0; q < 4; ++q) {
                e[q]  = __shfl(ex, half + j + q);
                ss[q] = __shfl(s,  half + j + q);
            }
            float v0[4], v1[4], v2[4];
#pragma unroll
            for (int q = 0; q < 4; ++q) {
                const float* p = H + (size_t)ss[q] * HID + c;
                v0[q] = p[0]; v1[q] = p[1]; v2[q] = p[2];
            }
#pragma unroll
            for (int q = 0; q < 4; ++q) {
                acc0 += e[q] * v0[q]; acc1 += e[q] * v1[q]; acc2 += e[q] * v2[q];
            }
        }
        for (; j < cnt; ++j) {
            float bex = __shfl(ex, half + j);
            int   bs  = __shfl(s,  half + j);
            const float* hp = H + (size_t)bs * HID + c;
            acc0 += bex * hp[0]; acc1 += bex * hp[1]; acc2 += bex * hp[2];
        }
    }
#pragma unroll
    for (int w = 16; w >= 1; w >>= 1) denom += __shfl_xor(denom, w);
    float inv = 1.f / (denom + 1e-16f);
    float o0 = acc0 * inv + bias[c];
    float o1 = acc1 * inv + bias[c + 1];
    float o2 = acc2 * inv + bias[c + 2];
    if (apply_leaky) { o0 = leaky(o0, 0.01f); o1 = leaky(o1, 0.01f); o2 = leaky(o2, 0.01f); }
    Hout[team * HID + c]     = o0;
    Hout[team * HID + c + 1] = o1;
    Hout[team * HID + c + 2] = o2;
}

// ---------------- global mean pool (fused count+sum, batch sorted) ----------------
__global__ __launch_bounds__(256) void pool_sum(
    const float* __restrict__ H, const int* __restrict__ batch,
    float* __restrict__ sums, float* __restrict__ counts) {
    int team = (blockIdx.x * blockDim.x + threadIdx.x) >> 5;
    int lane = threadIdx.x & 31;
    int c = lane * 3;
    int n0 = team * 32;
    if (n0 >= N_NODES) return;
    int n1 = min(n0 + 32, N_NODES);
    float a0 = 0.f, a1 = 0.f, a2 = 0.f;
    int cur = batch[n0], runlen = 0;
    for (int n = n0; n < n1; ++n) {
        int g = batch[n];
        if (g != cur) {
            atomicAdd(&sums[cur * HID + c],     a0);
            atomicAdd(&sums[cur * HID + c + 1], a1);
            atomicAdd(&sums[cur * HID + c + 2], a2);
            if (lane == 0) atomicAdd(&counts[cur], (float)runlen);
            a0 = a1 = a2 = 0.f; cur = g; runlen = 0;
        }
        const float* hp = H + (size_t)n * HID + c;
        a0 += hp[0]; a1 += hp[1]; a2 += hp[2];
        ++runlen;
    }
    atomicAdd(&sums[cur * HID + c],     a0);
    atomicAdd(&sums[cur * HID + c + 1], a1);
    atomicAdd(&sums[cur * HID + c + 2], a2);
    if (lane == 0) atomicAdd(&counts[cur], (float)runlen);
}

__global__ void finalize(const float* __restrict__ sums, const float* __restrict__ counts,
                         float* __restrict__ out) {
    int i = blockIdx.x * blockDim.x + threadIdx.x;
    if (i < NUM_GRAPHS * HID) out[i] = sums[i] / fmaxf(counts[i / HID], 1.f);
}

// ---------------- launch ----------------
extern "C" void kernel_launch(void* const* d_in, const int* in_sizes, int n_in,
                              void* d_out, int out_size, void* d_ws, size_t ws_size,
                              hipStream_t stream) {
    const float* x     = (const float*)d_in[0];
    const int*   ei    = (const int*)d_in[1];
    const int*   srcI  = ei;
    const int*   dstI  = ei + N_EDGES;
    const int*   batch = (const int*)d_in[2];
    const float* W1 = (const float*)d_in[3],  *as1 = (const float*)d_in[4],
               * ad1 = (const float*)d_in[5], *b1  = (const float*)d_in[6];
    const float* W2 = (const float*)d_in[7],  *as2 = (const float*)d_in[8],
               * ad2 = (const float*)d_in[9], *b2  = (const float*)d_in[10];
    const float* W3 = (const float*)d_in[11], *as3 = (const float*)d_in[12],
               * ad3 = (const float*)d_in[13], *b3 = (const float*)d_in[14];
    float* out = (float*)d_out;

    // workspace layout (all 16B-aligned by construction)
    char* p = (char*)d_ws;
    float* h0 = (float*)p;  p += (size_t)N_NODES * HID * 4;
    float* h1 = (float*)p;  p += (size_t)N_NODES * HID * 4;
    float* As = (float*)p;  p += (size_t)N_NODES * 4;
    float* Ad = (float*)p;  p += (size_t)N_NODES * 4;
    int* offs = (int*)p;    p += (size_t)(N_NODES + 4) * 4;
    int* csr  = (int*)p;    p += (size_t)E_TOT * 4;
    int* bsum = (int*)p;    p += 64 * 4;
    int* excl = (int*)p;    p += 64 * 4;
    // contiguous zero-region: sums | counts | deg | cursor
    char* zbase = p;
    float* sums   = (float*)p; p += (size_t)NUM_GRAPHS * HID * 4;
    float* counts = (float*)p; p += (size_t)NUM_GRAPHS * 4;
    int* deg    = (int*)p;  p += (size_t)N_NODES * 4;
    int* cursor = (int*)p;  p += (size_t)N_NODES * 4;
    size_t zbytes = (size_t)(p - zbase);

    hipMemsetAsync(zbase, 0, zbytes, stream);

    int eb = (E_TOT + 255) / 256;
    count_deg<<<eb, 256, 0, stream>>>(dstI, deg);
    block_sums<<<NB, 256, 0, stream>>>(deg, bsum);
    scan_partials<<<1, 64, 0, stream>>>(bsum, excl, offs);
    write_offs<<<NB, 256, 0, stream>>>(deg, excl, offs);
    scatter_edges<<<eb, 256, 0, stream>>>(srcI, dstI, offs, cursor, csr);

    int gemmGrid = (N_NODES + 63) / 64;    // 782 blocks
    int aggGrid  = (N_NODES * 32) / 256;   // exact: 6250

    // layer 1
    gemm_tiled<IN0><<<gemmGrid, 256, 0, stream>>>(x, W1, as1, ad1, h0, As, Ad);
    aggregate<<<aggGrid, 256, 0, stream>>>(h0, As, Ad, offs, csr, b1, h1, 1);
    // layer 2
    gemm_tiled<HID><<<gemmGrid, 256, 0, stream>>>(h1, W2, as2, ad2, h0, As, Ad);
    aggregate<<<aggGrid, 256, 0, stream>>>(h0, As, Ad, offs, csr, b2, h1, 1);
    // layer 3
    gemm_tiled<HID><<<gemmGrid, 256, 0, stream>>>(h1, W3, as3, ad3, h0, As, Ad);
    aggregate<<<aggGrid, 256, 0, stream>>>(h0, As, Ad, offs, csr, b3, h1, 0);

    // mean pool
    int teams = (N_NODES + 31) / 32;
    pool_sum<<<(teams * 32 + 255) / 256, 256, 0, stream>>>(h1, batch, sums, counts);
    finalize<<<(NUM_GRAPHS * HID + 255) / 256, 256, 0, stream>>>(sums, counts, out);
}

// Round 9
// 427.638 us; speedup vs baseline: 1.4191x; 1.1556x over previous
//
#include <hip/hip_runtime.h>

#define N_NODES 50000
#define N_EDGES 800000
#define E_TOT   850000      // + self loops
#define IN0     128
#define HID     96
#define NUM_GRAPHS 64
#define NB      ((N_NODES + 1023) / 1024)   // 49 scan blocks

__device__ __forceinline__ float leaky(float x, float s) { return x > 0.f ? x : s * x; }

// ---------------- CSR build ----------------
__global__ void count_deg(const int* __restrict__ dst, int* __restrict__ deg) {
    int e = blockIdx.x * blockDim.x + threadIdx.x;
    if (e >= E_TOT) return;
    int d = (e < N_EDGES) ? dst[e] : (e - N_EDGES);   // appended self loops
    atomicAdd(&deg[d], 1);
}

// 3-kernel multi-block exclusive scan of deg -> offs
__global__ __launch_bounds__(256) void block_sums(const int* __restrict__ deg, int* __restrict__ bsum) {
    int b = blockIdx.x, t = threadIdx.x;
    int base = b * 1024 + t * 4;
    int s = 0;
    if (base + 3 < N_NODES) {
        int4 v = *(const int4*)(deg + base);
        s = v.x + v.y + v.z + v.w;
    } else {
        for (int k = 0; k < 4; ++k) if (base + k < N_NODES) s += deg[base + k];
    }
#pragma unroll
    for (int w = 32; w >= 1; w >>= 1) s += __shfl_xor(s, w);
    __shared__ int ws[4];
    if ((t & 63) == 0) ws[t >> 6] = s;
    __syncthreads();
    if (t == 0) bsum[b] = ws[0] + ws[1] + ws[2] + ws[3];
}

__global__ void scan_partials(const int* __restrict__ bsum, int* __restrict__ excl, int* __restrict__ offs) {
    int t = threadIdx.x;   // 64 threads
    int v = (t < NB) ? bsum[t] : 0;
    int incl = v;
#pragma unroll
    for (int d = 1; d < 64; d <<= 1) {
        int u = __shfl_up(incl, d);
        if (t >= d) incl += u;
    }
    if (t < NB) excl[t] = incl - v;
    if (t == 0) offs[N_NODES] = E_TOT;
}

__global__ __launch_bounds__(256) void write_offs(const int* __restrict__ deg,
                                                  const int* __restrict__ excl,
                                                  int* __restrict__ offs) {
    __shared__ int sh[256];
    int b = blockIdx.x, t = threadIdx.x;
    int base = b * 1024 + t * 4;
    int d0 = 0, d1 = 0, d2 = 0, d3 = 0;
    if (base + 3 < N_NODES) {
        int4 v = *(const int4*)(deg + base);
        d0 = v.x; d1 = v.y; d2 = v.z; d3 = v.w;
    } else {
        if (base     < N_NODES) d0 = deg[base];
        if (base + 1 < N_NODES) d1 = deg[base + 1];
        if (base + 2 < N_NODES) d2 = deg[base + 2];
    }
    int tsum = d0 + d1 + d2 + d3;
    sh[t] = tsum;
    __syncthreads();
    for (int off = 1; off < 256; off <<= 1) {
        int u = (t >= off) ? sh[t - off] : 0;
        __syncthreads();
        sh[t] += u;
        __syncthreads();
    }
    int ebase = excl[b] + sh[t] - tsum;
    if (base + 3 < N_NODES) {
        int4 o; o.x = ebase; o.y = ebase + d0; o.z = ebase + d0 + d1; o.w = ebase + d0 + d1 + d2;
        *(int4*)(offs + base) = o;
    } else {
        if (base     < N_NODES) offs[base]     = ebase;
        if (base + 1 < N_NODES) offs[base + 1] = ebase + d0;
        if (base + 2 < N_NODES) offs[base + 2] = ebase + d0 + d1;
    }
}

__global__ void scatter_edges(const int* __restrict__ src, const int* __restrict__ dst,
                              const int* __restrict__ offs, int* __restrict__ cursor,
                              int* __restrict__ csr) {
    int e = blockIdx.x * blockDim.x + threadIdx.x;
    if (e >= E_TOT) return;
    int s, d;
    if (e < N_EDGES) { s = src[e]; d = dst[e]; }
    else             { s = e - N_EDGES; d = s; }
    int pos = offs[d] + atomicAdd(&cursor[d], 1);
    csr[pos] = s;
}

// ---------------- K-tiled GEMM + attention logits ----------------
// 512 threads, block = 64 rows x 96 cols, K tiled by 32. Thread (cx=tid&31,
// ry=tid>>5) owns 4 rows x 3 cols -> acc=12 regs: fits 128-VGPR cap WITHOUT
// spilling (R8's 24-acc version spilled: WRITE_SIZE 19->48 MB = scratch).
template <int IN>
__global__ __launch_bounds__(512, 4) void gemm_tiled(
    const float* __restrict__ X, const float* __restrict__ W,
    const float* __restrict__ asrc, const float* __restrict__ adst,
    float* __restrict__ H, float* __restrict__ As, float* __restrict__ Ad) {
    __shared__ float Xs[64 * 36];   // 9216 B
    __shared__ float Wt[96 * 36];   // 13824 B
    int tid = threadIdx.x;
    int cx = tid & 31, ry = tid >> 5;   // ry 0..15: rows ry*4 .. ry*4+3
    int cbase = cx * 3;
    int rowBase = blockIdx.x * 64;
    const float* w0p = &Wt[(cbase + 0) * 36];
    const float* w1p = &Wt[(cbase + 1) * 36];
    const float* w2p = &Wt[(cbase + 2) * 36];
    const float* xsp = &Xs[ry * 4 * 36];
    float acc[4][3];
#pragma unroll
    for (int r = 0; r < 4; ++r)
#pragma unroll
        for (int j = 0; j < 3; ++j) acc[r][j] = 0.f;

    for (int t = 0; t < IN / 32; ++t) {
        int k0 = t * 32;
        __syncthreads();   // previous tile's reads done before overwrite
        // stage X tile: 64 rows x 32 k (512 float4, 1 per thread)
        {
            int row = tid >> 3;
            int kk = (tid & 7) * 4;
            int grow = rowBase + row;
            float4 v = make_float4(0.f, 0.f, 0.f, 0.f);
            if (grow < N_NODES) v = *(const float4*)(X + (size_t)grow * IN + k0 + kk);
            *(float4*)(&Xs[row * 36 + kk]) = v;
        }
        // stage W tile transposed: 32 k x 96 c -> Wt[c][k] (6 floats per thread)
#pragma unroll
        for (int j = 0; j < 6; ++j) {
            int f = tid + j * 512;
            int kk = f / 96;
            int c = f - kk * 96;
            Wt[c * 36 + kk] = W[(size_t)(k0 + kk) * HID + c];
        }
        __syncthreads();
        // compute: all b128 LDS reads
#pragma unroll 2
        for (int k = 0; k < 32; k += 4) {
            float4 w0 = *(const float4*)(w0p + k);
            float4 w1 = *(const float4*)(w1p + k);
            float4 w2 = *(const float4*)(w2p + k);
#pragma unroll
            for (int r = 0; r < 4; ++r) {
                float4 xv = *(const float4*)(xsp + r * 36 + k);
                acc[r][0] += xv.x * w0.x + xv.y * w0.y + xv.z * w0.z + xv.w * w0.w;
                acc[r][1] += xv.x * w1.x + xv.y * w1.y + xv.z * w1.z + xv.w * w1.w;
                acc[r][2] += xv.x * w2.x + xv.y * w2.y + xv.z * w2.z + xv.w * w2.w;
            }
        }
    }
    // epilogue: store H, alpha dots, 32-lane shfl reduce (xor<=16 stays in half-wave)
    float a0 = asrc[cbase], a1 = asrc[cbase + 1], a2 = asrc[cbase + 2];
    float d0 = adst[cbase], d1 = adst[cbase + 1], d2 = adst[cbase + 2];
#pragma unroll
    for (int r = 0; r < 4; ++r) {
        int row = rowBase + ry * 4 + r;
        bool valid = row < N_NODES;   // uniform across the 32 cx lanes
        float ps = acc[r][0] * a0 + acc[r][1] * a1 + acc[r][2] * a2;
        float pd = acc[r][0] * d0 + acc[r][1] * d1 + acc[r][2] * d2;
#pragma unroll
        for (int w = 16; w >= 1; w >>= 1) {
            ps += __shfl_xor(ps, w);
            pd += __shfl_xor(pd, w);
        }
        if (valid) {
            float* hr = H + (size_t)row * HID + cbase;
            hr[0] = acc[r][0]; hr[1] = acc[r][1]; hr[2] = acc[r][2];
            if (cx == 0) { As[row] = ps; Ad[row] = pd; }
        }
    }
}

// ---------------- CSR softmax-aggregate (no max pass; shift by self-loop logit) --------
__global__ __launch_bounds__(256) void aggregate(
    const float* __restrict__ H, const float* __restrict__ As, const float* __restrict__ Ad,
    const int* __restrict__ offs, const int* __restrict__ csr,
    const float* __restrict__ bias, float* __restrict__ Hout, int apply_leaky) {
    int team = (blockIdx.x * blockDim.x + threadIdx.x) >> 5;   // == node
    int lane = threadIdx.x & 31;
    int half = threadIdx.x & 32;   // wave64 half base for shfl
    int start = offs[team], end = offs[team + 1];
    float ad = Ad[team];
    // softmax shift: self-loop logit (free, no gather; denom >= 1)
    float m = leaky(As[team] + ad, 0.2f);
    float acc0 = 0.f, acc1 = 0.f, acc2 = 0.f, denom = 0.f;
    int c = lane * 3;
    for (int base = start; base < end; base += 32) {
        int i = base + lane;
        bool valid = i < end;
        int s = valid ? csr[i] : 0;
        float ex = 0.f;
        if (valid) ex = __expf(leaky(As[s] + ad, 0.2f) - m);
        denom += ex;
        int cnt = min(32, end - base);
        int j = 0;
        for (; j + 8 <= cnt; j += 8) {
            float e[8]; int ss[8];
#pragma unroll
            for (int q = 0; q < 8; ++q) {
                e[q]  = __shfl(ex, half + j + q);
                ss[q] = __shfl(s,  half + j + q);
            }
            float v0[8], v1[8], v2[8];
#pragma unroll
            for (int q = 0; q < 8; ++q) {
                const float* p = H + (size_t)ss[q] * HID + c;
                v0[q] = p[0]; v1[q] = p[1]; v2[q] = p[2];
            }
#pragma unroll
            for (int q = 0; q < 8; ++q) {
                acc0 += e[q] * v0[q]; acc1 += e[q] * v1[q]; acc2 += e[q] * v2[q];
            }
        }
        for (; j + 4 <= cnt; j += 4) {
            float e[4]; int ss[4];
#pragma unroll
            for (int q = 0; q < 4; ++q) {
                e[q]  = __shfl(ex, half + j + q);
                ss[q] = __shfl(s,  half + j + q);
            }
            float v0[4], v1[4], v2[4];
#pragma unroll
            for (int q = 0; q < 4; ++q) {
                const float* p = H + (size_t)ss[q] * HID + c;
                v0[q] = p[0]; v1[q] = p[1]; v2[q] = p[2];
            }
#pragma unroll
            for (int q = 0; q < 4; ++q) {
                acc0 += e[q] * v0[q]; acc1 += e[q] * v1[q]; acc2 += e[q] * v2[q];
            }
        }
        for (; j < cnt; ++j) {
            float bex = __shfl(ex, half + j);
            int   bs  = __shfl(s,  half + j);
            const float* hp = H + (size_t)bs * HID + c;
            acc0 += bex * hp[0]; acc1 += bex * hp[1]; acc2 += bex * hp[2];
        }
    }
#pragma unroll
    for (int w = 16; w >= 1; w >>= 1) denom += __shfl_xor(denom, w);
    float inv = 1.f / (denom + 1e-16f);
    float o0 = acc0 * inv + bias[c];
    float o1 = acc1 * inv + bias[c + 1];
    float o2 = acc2 * inv + bias[c + 2];
    if (apply_leaky) { o0 = leaky(o0, 0.01f); o1 = leaky(o1, 0.01f); o2 = leaky(o2, 0.01f); }
    Hout[team * HID + c]     = o0;
    Hout[team * HID + c + 1] = o1;
    Hout[team * HID + c + 2] = o2;
}

// ---------------- global mean pool (fused count+sum, batch sorted) ----------------
__global__ __launch_bounds__(256) void pool_sum(
    const float* __restrict__ H, const int* __restrict__ batch,
    float* __restrict__ sums, float* __restrict__ counts) {
    int team = (blockIdx.x * blockDim.x + threadIdx.x) >> 5;
    int lane = threadIdx.x & 31;
    int c = lane * 3;
    int n0 = team * 32;
    if (n0 >= N_NODES) return;
    int n1 = min(n0 + 32, N_NODES);
    float a0 = 0.f, a1 = 0.f, a2 = 0.f;
    int cur = batch[n0], runlen = 0;
    for (int n = n0; n < n1; ++n) {
        int g = batch[n];
        if (g != cur) {
            atomicAdd(&sums[cur * HID + c],     a0);
            atomicAdd(&sums[cur * HID + c + 1], a1);
            atomicAdd(&sums[cur * HID + c + 2], a2);
            if (lane == 0) atomicAdd(&counts[cur], (float)runlen);
            a0 = a1 = a2 = 0.f; cur = g; runlen = 0;
        }
        const float* hp = H + (size_t)n * HID + c;
        a0 += hp[0]; a1 += hp[1]; a2 += hp[2];
        ++runlen;
    }
    atomicAdd(&sums[cur * HID + c],     a0);
    atomicAdd(&sums[cur * HID + c + 1], a1);
    atomicAdd(&sums[cur * HID + c + 2], a2);
    if (lane == 0) atomicAdd(&counts[cur], (float)runlen);
}

__global__ void finalize(const float* __restrict__ sums, const float* __restrict__ counts,
                         float* __restrict__ out) {
    int i = blockIdx.x * blockDim.x + threadIdx.x;
    if (i < NUM_GRAPHS * HID) out[i] = sums[i] / fmaxf(counts[i / HID], 1.f);
}

// ---------------- launch ----------------
extern "C" void kernel_launch(void* const* d_in, const int* in_sizes, int n_in,
                              void* d_out, int out_size, void* d_ws, size_t ws_size,
                              hipStream_t stream) {
    const float* x     = (const float*)d_in[0];
    const int*   ei    = (const int*)d_in[1];
    const int*   srcI  = ei;
    const int*   dstI  = ei + N_EDGES;
    const int*   batch = (const int*)d_in[2];
    const float* W1 = (const float*)d_in[3],  *as1 = (const float*)d_in[4],
               * ad1 = (const float*)d_in[5], *b1  = (const float*)d_in[6];
    const float* W2 = (const float*)d_in[7],  *as2 = (const float*)d_in[8],
               * ad2 = (const float*)d_in[9], *b2  = (const float*)d_in[10];
    const float* W3 = (const float*)d_in[11], *as3 = (const float*)d_in[12],
               * ad3 = (const float*)d_in[13], *b3 = (const float*)d_in[14];
    float* out = (float*)d_out;

    // workspace layout (all 16B-aligned by construction)
    char* p = (char*)d_ws;
    float* h0 = (float*)p;  p += (size_t)N_NODES * HID * 4;
    float* h1 = (float*)p;  p += (size_t)N_NODES * HID * 4;
    float* As = (float*)p;  p += (size_t)N_NODES * 4;
    float* Ad = (float*)p;  p += (size_t)N_NODES * 4;
    int* offs = (int*)p;    p += (size_t)(N_NODES + 4) * 4;
    int* csr  = (int*)p;    p += (size_t)E_TOT * 4;
    int* bsum = (int*)p;    p += 64 * 4;
    int* excl = (int*)p;    p += 64 * 4;
    // contiguous zero-region: sums | counts | deg | cursor
    char* zbase = p;
    float* sums   = (float*)p; p += (size_t)NUM_GRAPHS * HID * 4;
    float* counts = (float*)p; p += (size_t)NUM_GRAPHS * 4;
    int* deg    = (int*)p;  p += (size_t)N_NODES * 4;
    int* cursor = (int*)p;  p += (size_t)N_NODES * 4;
    size_t zbytes = (size_t)(p - zbase);

    hipMemsetAsync(zbase, 0, zbytes, stream);

    int eb = (E_TOT + 255) / 256;
    count_deg<<<eb, 256, 0, stream>>>(dstI, deg);
    block_sums<<<NB, 256, 0, stream>>>(deg, bsum);
    scan_partials<<<1, 64, 0, stream>>>(bsum, excl, offs);
    write_offs<<<NB, 256, 0, stream>>>(deg, excl, offs);
    scatter_edges<<<eb, 256, 0, stream>>>(srcI, dstI, offs, cursor, csr);

    int gemmGrid = (N_NODES + 63) / 64;    // 782 blocks
    int aggGrid  = (N_NODES * 32) / 256;   // exact: 6250

    // layer 1
    gemm_tiled<IN0><<<gemmGrid, 512, 0, stream>>>(x, W1, as1, ad1, h0, As, Ad);
    aggregate<<<aggGrid, 256, 0, stream>>>(h0, As, Ad, offs, csr, b1, h1, 1);
    // layer 2
    gemm_tiled<HID><<<gemmGrid, 512, 0, stream>>>(h1, W2, as2, ad2, h0, As, Ad);
    aggregate<<<aggGrid, 256, 0, stream>>>(h0, As, Ad, offs, csr, b2, h1, 1);
    // layer 3
    gemm_tiled<HID><<<gemmGrid, 512, 0, stream>>>(h1, W3, as3, ad3, h0, As, Ad);
    aggregate<<<aggGrid, 256, 0, stream>>>(h0, As, Ad, offs, csr, b3, h1, 0);

    // mean pool
    int teams = (N_NODES + 31) / 32;
    pool_sum<<<(teams * 32 + 255) / 256, 256, 0, stream>>>(h1, batch, sums, counts);
    finalize<<<(NUM_GRAPHS * HID + 255) / 256, 256, 0, stream>>>(sums, counts, out);
}